// Round 11
// baseline (949.745 us; speedup 1.0000x reference)
//
#include <hip/hip_runtime.h>
#include <hip/hip_bf16.h>

// B=8, N=256, D=E=G=MID=OUT=128
#define B_ 8
#define N_ 256
#define C_ 128
#define S_ 8
#define STEPB (N_ * C_ * 4)   // 128KB between consecutive i in edge

typedef __attribute__((ext_vector_type(4))) float f32x4;
typedef __attribute__((ext_vector_type(8))) short s16x8;

typedef __attribute__((address_space(1))) const void gas_void;
typedef __attribute__((address_space(3))) void las_void;

__device__ __forceinline__ unsigned short f2bf(float f) {
  unsigned int u = __builtin_bit_cast(unsigned int, f);
  u += 0x7FFFu + ((u >> 16) & 1u);   // RNE
  return (unsigned short)(u >> 16);
}

__device__ __forceinline__ unsigned int pk2(float a, float b) {
  __hip_bfloat162 h = __float22bfloat162_rn(make_float2(a, b));
  unsigned int u;
  __builtin_memcpy(&u, &h, 4);
  return u;
}

__device__ __forceinline__ s16x8 cvt8(f32x4 lo, f32x4 hi) {
  union { unsigned int u[4]; s16x8 s; } r;
  r.u[0] = pk2(lo[0], lo[1]);
  r.u[1] = pk2(lo[2], lo[3]);
  r.u[2] = pk2(hi[0], hi[1]);
  r.u[3] = pk2(hi[2], hi[3]);
  return r.s;
}

// ---------- P: ws_c, ws_mh2 (bf16 frag-packed), ws_B, ws_adj. reps-idempotent. ----------
__global__ void k_pro(const float* __restrict__ node, const float* __restrict__ hidden,
                      const float* __restrict__ graph, const int* __restrict__ adjm,
                      const float* __restrict__ Wn, const float* __restrict__ bn,
                      const float* __restrict__ Wh, const float* __restrict__ bh,
                      const float* __restrict__ be,
                      const float* __restrict__ Wg, const float* __restrict__ bg,
                      const float* __restrict__ We,
                      float* __restrict__ ws_c, unsigned short* __restrict__ ws_mh2,
                      short* __restrict__ ws_B, unsigned char* __restrict__ ws_adj,
                      int reps) {
  int bid = blockIdx.x, t = threadIdx.x;
  if (bid >= 544) {
    for (int rep = 0; rep < reps; ++rep) {
      int base = (bid - 544) * 1024 + t * 8;
      int4 a = *reinterpret_cast<const int4*>(adjm + base);
      int4 c = *reinterpret_cast<const int4*>(adjm + base + 4);
      uint2 v;
      v.x = (unsigned)a.x | ((unsigned)a.y << 8) | ((unsigned)a.z << 16) | ((unsigned)a.w << 24);
      v.y = (unsigned)c.x | ((unsigned)c.y << 8) | ((unsigned)c.z << 16) | ((unsigned)c.w << 24);
      *reinterpret_cast<uint2*>(ws_adj + base) = v;
    }
    return;
  }
  if (bid >= 512) {
    for (int rep = 0; rep < reps; ++rep) {
      int f = bid - 512;
      if (t < 64) {
        int kb = f >> 3, nbg = f & 7;
        int lr = t & 15, lg = t >> 4;
        s16x8 v;
#pragma unroll
        for (int e = 0; e < 8; ++e)
          v[e] = (short)f2bf(We[(kb * 32 + lg * 8 + e) * C_ + nbg * 16 + lr]);
        *reinterpret_cast<s16x8*>(ws_B + (f * 64 + t) * 8) = v;
      }
    }
    return;
  }
  bool isc = bid < 256;
  int row0 = (isc ? bid : bid - 256) * 8;
  const float* src = isc ? node : hidden;
  const float* W   = isc ? Wn : Wh;
  __shared__ float sh[8][C_];
  for (int rep = 0; rep < reps; ++rep) {
#pragma unroll
    for (int r = 0; r < 8; ++r) sh[r][t] = src[(row0 + r) * C_ + t];
    __syncthreads();
    float g = 0.f;
    float acc[8];
#pragma unroll
    for (int r = 0; r < 8; ++r) acc[r] = 0.f;
    const float* gr = graph + (row0 >> 8) * C_;
    for (int k = 0; k < C_; k += 8) {
      float wv[8];
#pragma unroll
      for (int u = 0; u < 8; ++u) wv[u] = W[(k + u) * C_ + t];
      if (isc) {
        float wgv[8];
#pragma unroll
        for (int u = 0; u < 8; ++u) wgv[u] = Wg[(k + u) * C_ + t];
#pragma unroll
        for (int u = 0; u < 8; ++u) g += gr[k + u] * wgv[u];
      }
#pragma unroll
      for (int u = 0; u < 8; ++u)
#pragma unroll
        for (int r = 0; r < 8; ++r) acc[r] += sh[r][k + u] * wv[u];
    }
    if (isc) {
      float init = bn[t] + be[t] + bg[t] + g;
#pragma unroll
      for (int r = 0; r < 8; ++r) ws_c[(row0 + r) * C_ + t] = acc[r] + init;
    } else {
      float init = bh[t];
      int p = (t >> 5) * 32 + (t & 15) * 2 + ((t >> 4) & 1);
#pragma unroll
      for (int r = 0; r < 8; ++r) ws_mh2[(row0 + r) * C_ + p] = f2bf(acc[r] + init);
    }
    __syncthreads();
  }
}

// ---------- Main: identical structure to R10; reps loop wraps prologue+steady+write.
// All rep-boundary races rewrite identical bytes (idempotent) -> benign. ----------
__global__ __launch_bounds__(256, 4) void k_main(
    const float* __restrict__ edge, const unsigned char* __restrict__ ws_adj,
    const short* __restrict__ ws_B,
    const float* __restrict__ ws_c, const unsigned short* __restrict__ ws_mh2,
    float* __restrict__ pbuf, int reps) {
  __shared__ __align__(16) char smem[3 * 8192 + 8192 + 512];
  char* ring    = smem;
  char* mh_lds  = smem + 24576;
  char* adj_lds = smem + 24576 + 8192;
  const int lane = threadIdx.x & 63;
  const int w = threadIdx.x >> 6;
  const int wg = blockIdx.x;
  const int s   = wg & 7;
  const int j16 = (wg >> 3) & 15;
  const int b   = wg >> 7;
  const int j0 = j16 * 16;
  const int n0 = w * 32;
  const int i0 = s * 32;
  const int lr = lane & 15;
  const int lg = lane >> 4;

  s16x8 bfrag[4][2];
#pragma unroll
  for (int kb = 0; kb < 4; ++kb)
#pragma unroll
    for (int nb = 0; nb < 2; ++nb)
      bfrag[kb][nb] = *reinterpret_cast<const s16x8*>(
          ws_B + ((kb * 8 + w * 2 + nb) * 64 + lane) * 8);

  float cf[2][4];
#pragma unroll
  for (int nb = 0; nb < 2; ++nb)
#pragma unroll
    for (int r = 0; r < 4; ++r)
      cf[nb][r] = ws_c[(b * N_ + j0 + lg * 4 + r) * C_ + n0 + nb * 16 + lr];

  const char* gedge = (const char*)(edge + ((size_t)(b * N_ + i0) * N_ + j0) * C_);

  int soff[2];
#pragma unroll
  for (int q = 0; q < 2; ++q) {
    int y = w * 2048 + q * 1024 + lane * 16;
    int row = y >> 9;
    soff[q] = y ^ ((row & 7) << 4);
  }
  const int base0 = lr * 512 + lg * 32;
  const int swz = (lr & 7) << 4;

#define GLL16(GP, LP) __builtin_amdgcn_global_load_lds((gas_void*)(GP), (las_void*)(LP), 16, 0, 0)
#define GLL4(GP, LP)  __builtin_amdgcn_global_load_lds((gas_void*)(GP), (las_void*)(LP), 4, 0, 0)

#define ISSUE(SL, TT) do { \
    const char* gch = gedge + (size_t)(TT) * STEPB; \
    char* lb = ring + (SL) * 8192 + w * 2048; \
    GLL16(gch + soff[0], lb); \
    GLL16(gch + soff[1], lb + 1024); \
  } while (0)

#define STEP(SL, ISL, WAITN, DOISSUE, TI, T) do { \
    asm volatile("s_waitcnt vmcnt(" WAITN ")\n\ts_barrier" ::: "memory"); \
    if (DOISSUE) ISSUE(ISL, TI); \
    const char* rb = ring + (SL) * 8192; \
    s16x8 af[4]; \
    _Pragma("unroll") \
    for (int kb = 0; kb < 4; ++kb) { \
      int a0 = (base0 + kb * 128) ^ swz; \
      f32x4 lo = *reinterpret_cast<const f32x4*>(rb + a0); \
      f32x4 hi = *reinterpret_cast<const f32x4*>(rb + (a0 ^ 16)); \
      af[kb] = cvt8(lo, hi); \
    } \
    unsigned int mw = *reinterpret_cast<const unsigned int*>(mh_lds + (T) * 256 + w * 64 + lr * 4); \
    unsigned int ab = *reinterpret_cast<const unsigned int*>(adj_lds + (T) * 16 + lg * 4); \
    float mh0 = __builtin_bit_cast(float, mw << 16); \
    float mh1 = __builtin_bit_cast(float, mw & 0xffff0000u); \
    float adjf[4] = {(float)(ab & 0xff), (float)((ab >> 8) & 0xff), \
                     (float)((ab >> 16) & 0xff), (float)(ab >> 24)}; \
    _Pragma("unroll") \
    for (int nb = 0; nb < 2; ++nb) { \
      f32x4 acc; \
      float mhv = nb ? mh1 : mh0; \
      _Pragma("unroll") \
      for (int r = 0; r < 4; ++r) acc[r] = cf[nb][r] + mhv; \
      _Pragma("unroll") \
      for (int kb = 0; kb < 4; ++kb) \
        acc = __builtin_amdgcn_mfma_f32_16x16x32_bf16(af[kb], bfrag[kb][nb], acc, 0, 0, 0); \
      _Pragma("unroll") \
      for (int r = 0; r < 4; ++r) mx[nb][r] = fmaxf(mx[nb][r], adjf[r] * acc[r]); \
    } \
  } while (0)

  for (int rep = 0; rep < reps; ++rep) {
    f32x4 mx[2];
#pragma unroll
    for (int nb = 0; nb < 2; ++nb)
#pragma unroll
      for (int r = 0; r < 4; ++r) mx[nb][r] = -INFINITY;

    {
      const char* mh_g = (const char*)(ws_mh2 + ((size_t)(b * N_) + i0) * C_);
      GLL16(mh_g + w * 2048 + lane * 16, mh_lds + w * 2048);
      GLL16(mh_g + w * 2048 + 1024 + lane * 16, mh_lds + w * 2048 + 1024);
      const char* adj_g = (const char*)(ws_adj + ((size_t)(b * N_) + i0) * N_ + j0);
      GLL4(adj_g + (lane >> 2) * N_ + (lane & 3) * 4, adj_lds);
      GLL4(adj_g + ((lane >> 2) + 16) * N_ + (lane & 3) * 4, adj_lds + 256);
    }
    ISSUE(0, 0);
    ISSUE(1, 1);
    asm volatile("s_waitcnt vmcnt(4)\n\ts_barrier" ::: "memory");

    for (int o = 0; o < 10; ++o) {
      STEP(0, 2, "2", 1, 3 * o + 2, 3 * o);
      STEP(1, 0, "2", 1, 3 * o + 3, 3 * o + 1);
      STEP(2, 1, "2", 1, 3 * o + 4, 3 * o + 2);
    }
    STEP(0, 2, "2", 0, 0, 30);
    STEP(1, 0, "0", 0, 0, 31);

    float* prow = pbuf + (((size_t)s * B_ + b) * N_ + j0 + lg * 4) * C_ + n0 + lr;
#pragma unroll
    for (int nb = 0; nb < 2; ++nb)
#pragma unroll
      for (int r = 0; r < 4; ++r)
        prow[r * C_ + nb * 16] = mx[nb][r];
  }

#undef STEP
#undef ISSUE
#undef GLL16
#undef GLL4
}

// ---------- Epilogue: reps-idempotent ----------
__global__ void k_epi(const float* __restrict__ node, const float* __restrict__ hidden,
                      const float* __restrict__ Wo1, const float* __restrict__ bo1,
                      const float* __restrict__ Wo2, const float* __restrict__ bo2,
                      const float* __restrict__ Wo3, const float* __restrict__ bo3,
                      const float* __restrict__ pbuf, float* __restrict__ out, int reps) {
  int row0 = blockIdx.x * 4;
  int col = threadIdx.x & 127;
  int half = threadIdx.x >> 7;
  __shared__ float shn[4][C_], shh[4][C_], shm[4][C_];
  for (int rep = 0; rep < reps; ++rep) {
#pragma unroll
    for (int r = 0; r < 2; ++r) {
      int rr = half * 2 + r;
      shn[rr][col] = node[(row0 + rr) * C_ + col];
      shh[rr][col] = hidden[(row0 + rr) * C_ + col];
      float mv = -INFINITY;
#pragma unroll
      for (int s = 0; s < S_; ++s)
        mv = fmaxf(mv, pbuf[((size_t)s * (B_ * N_) + row0 + rr) * C_ + col]);
      shm[rr][col] = mv;
    }
    __syncthreads();
    float init = bo1[col] + bo2[col] + bo3[col];
    float acc[2];
    acc[0] = init; acc[1] = init;
    for (int k = 0; k < C_; k += 8) {
      float wv1[8], wv2[8], wv3[8];
#pragma unroll
      for (int u = 0; u < 8; ++u) {
        wv1[u] = Wo1[(k + u) * C_ + col];
        wv2[u] = Wo2[(k + u) * C_ + col];
        wv3[u] = Wo3[(k + u) * C_ + col];
      }
#pragma unroll
      for (int u = 0; u < 8; ++u)
#pragma unroll
        for (int r = 0; r < 2; ++r) {
          int rr = half * 2 + r;
          acc[r] += shn[rr][k + u] * wv1[u] + shh[rr][k + u] * wv2[u] + shm[rr][k + u] * wv3[u];
        }
    }
#pragma unroll
    for (int r = 0; r < 2; ++r)
      out[(row0 + half * 2 + r) * C_ + col] = acc[r];
    __syncthreads();
  }
}

extern "C" void kernel_launch(void* const* d_in, const int* in_sizes, int n_in,
                              void* d_out, int out_size, void* d_ws, size_t ws_size,
                              hipStream_t stream) {
  const float* node   = (const float*)d_in[0];
  const float* edge   = (const float*)d_in[1];
  const float* graph  = (const float*)d_in[2];
  const int*   adjm   = (const int*)d_in[3];
  const float* hidden = (const float*)d_in[4];
  const float* Wn = (const float*)d_in[5];  const float* bn = (const float*)d_in[6];
  const float* Wh = (const float*)d_in[7];  const float* bh = (const float*)d_in[8];
  const float* We = (const float*)d_in[9];  const float* be = (const float*)d_in[10];
  const float* Wg = (const float*)d_in[11]; const float* bg = (const float*)d_in[12];
  const float* Wo1 = (const float*)d_in[13]; const float* bo1 = (const float*)d_in[14];
  const float* Wo2 = (const float*)d_in[15]; const float* bo2 = (const float*)d_in[16];
  const float* Wo3 = (const float*)d_in[17]; const float* bo3 = (const float*)d_in[18];
  float* out = (float*)d_out;

  char* ws = (char*)d_ws;
  float*          ws_c   = (float*)ws;                            // 1 MB
  unsigned short* ws_mh2 = (unsigned short*)(ws + (1u << 20));    // 512 KB (bf16)
  short*          ws_B   = (short*)(ws + 1572864u);               // 32 KB
  unsigned char*  ws_adj = (unsigned char*)(ws + 1835008u);       // 512 KB
  float*          pbuf   = (float*)(ws + (4u << 20));             // 8 MB partials

  // MEASUREMENT ROUND: reps chosen so each dispatch exceeds the ~152us harness
  // fills and lands in the rocprof top-5 with full counters. Outputs identical
  // to reps=1 (idempotent recompute).
  k_pro<<<1056, 128, 0, stream>>>(node, hidden, graph, adjm, Wn, bn, Wh, bh, be,
                                  Wg, bg, We, ws_c, ws_mh2, ws_B, ws_adj, 48);
  k_main<<<1024, 256, 0, stream>>>(edge, ws_adj, ws_B, ws_c, ws_mh2, pbuf, 5);
  k_epi<<<512, 256, 0, stream>>>(node, hidden, Wo1, bo1, Wo2, bo2, Wo3, bo3,
                                 pbuf, out, 48);
}

// Round 12
// 75.710 us; speedup vs baseline: 12.5445x; 12.5445x over previous
//
#include <hip/hip_runtime.h>
#include <hip/hip_bf16.h>

// B=8, N=256, D=E=G=MID=OUT=128
#define B_ 8
#define N_ 256
#define C_ 128
#define S_ 8
#define STEPB (N_ * C_ * 4)   // 128KB per i-row of one batch

typedef __attribute__((ext_vector_type(4))) float f32x4;
typedef __attribute__((ext_vector_type(8))) short s16x8;

typedef __attribute__((address_space(1))) const void gas_void;
typedef __attribute__((address_space(3))) void las_void;

__device__ __forceinline__ unsigned short f2bf(float f) {
  unsigned int u = __builtin_bit_cast(unsigned int, f);
  u += 0x7FFFu + ((u >> 16) & 1u);   // RNE
  return (unsigned short)(u >> 16);
}

__device__ __forceinline__ unsigned int pk2(float a, float b) {
  __hip_bfloat162 h = __float22bfloat162_rn(make_float2(a, b));
  unsigned int u;
  __builtin_memcpy(&u, &h, 4);
  return u;
}

__device__ __forceinline__ s16x8 cvt8(f32x4 lo, f32x4 hi) {
  union { unsigned int u[4]; s16x8 s; } r;
  r.u[0] = pk2(lo[0], lo[1]);
  r.u[1] = pk2(lo[2], lo[3]);
  r.u[2] = pk2(hi[0], hi[1]);
  r.u[3] = pk2(hi[2], hi[3]);
  return r.s;
}

// ---------- P: ws_c, ws_mh2 (bf16 frag-packed), ws_B, ws_adj ----------
__global__ void k_pro(const float* __restrict__ node, const float* __restrict__ hidden,
                      const float* __restrict__ graph, const int* __restrict__ adjm,
                      const float* __restrict__ Wn, const float* __restrict__ bn,
                      const float* __restrict__ Wh, const float* __restrict__ bh,
                      const float* __restrict__ be,
                      const float* __restrict__ Wg, const float* __restrict__ bg,
                      const float* __restrict__ We,
                      float* __restrict__ ws_c, unsigned short* __restrict__ ws_mh2,
                      short* __restrict__ ws_B, unsigned char* __restrict__ ws_adj,
                      int reps) {
  int bid = blockIdx.x, t = threadIdx.x;
  if (bid >= 544) {
    for (int rep = 0; rep < reps; ++rep) {
      int base = (bid - 544) * 1024 + t * 8;
      int4 a = *reinterpret_cast<const int4*>(adjm + base);
      int4 c = *reinterpret_cast<const int4*>(adjm + base + 4);
      uint2 v;
      v.x = (unsigned)a.x | ((unsigned)a.y << 8) | ((unsigned)a.z << 16) | ((unsigned)a.w << 24);
      v.y = (unsigned)c.x | ((unsigned)c.y << 8) | ((unsigned)c.z << 16) | ((unsigned)c.w << 24);
      *reinterpret_cast<uint2*>(ws_adj + base) = v;
    }
    return;
  }
  if (bid >= 512) {
    for (int rep = 0; rep < reps; ++rep) {
      int f = bid - 512;
      if (t < 64) {
        int kb = f >> 3, nbg = f & 7;
        int lr = t & 15, lg = t >> 4;
        s16x8 v;
#pragma unroll
        for (int e = 0; e < 8; ++e)
          v[e] = (short)f2bf(We[(kb * 32 + lg * 8 + e) * C_ + nbg * 16 + lr]);
        *reinterpret_cast<s16x8*>(ws_B + (f * 64 + t) * 8) = v;
      }
    }
    return;
  }
  bool isc = bid < 256;
  int row0 = (isc ? bid : bid - 256) * 8;
  const float* src = isc ? node : hidden;
  const float* W   = isc ? Wn : Wh;
  __shared__ float sh[8][C_];
  for (int rep = 0; rep < reps; ++rep) {
#pragma unroll
    for (int r = 0; r < 8; ++r) sh[r][t] = src[(row0 + r) * C_ + t];
    __syncthreads();
    float g = 0.f;
    float acc[8];
#pragma unroll
    for (int r = 0; r < 8; ++r) acc[r] = 0.f;
    const float* gr = graph + (row0 >> 8) * C_;
    for (int k = 0; k < C_; k += 8) {
      float wv[8];
#pragma unroll
      for (int u = 0; u < 8; ++u) wv[u] = W[(k + u) * C_ + t];
      if (isc) {
        float wgv[8];
#pragma unroll
        for (int u = 0; u < 8; ++u) wgv[u] = Wg[(k + u) * C_ + t];
#pragma unroll
        for (int u = 0; u < 8; ++u) g += gr[k + u] * wgv[u];
      }
#pragma unroll
      for (int u = 0; u < 8; ++u)
#pragma unroll
        for (int r = 0; r < 8; ++r) acc[r] += sh[r][k + u] * wv[u];
    }
    if (isc) {
      float init = bn[t] + be[t] + bg[t] + g;
#pragma unroll
      for (int r = 0; r < 8; ++r) ws_c[(row0 + r) * C_ + t] = acc[r] + init;
    } else {
      float init = bh[t];
      int p = (t >> 5) * 32 + (t & 15) * 2 + ((t >> 4) & 1);
#pragma unroll
      for (int r = 0; r < 8; ++r) ws_mh2[(row0 + r) * C_ + p] = f2bf(acc[r] + init);
    }
    __syncthreads();
  }
}

// ---------- Main: fused edge@We + broadcast-add + masked max ----------
// XCD-locality mapping: b = wg & 7 (blockIdx%8 -> XCD round-robin, so one XCD
// owns one batch's 33.5MB slice); j16 = (wg>>3)&15 (same-XCD neighbors read
// adjacent 8KB); s = wg>>7 with INTERLEAVED i = s + 8t, so each XCD's 128
// blocks sweep a contiguous 1MB window per step, sequentially through the
// slice. Pipeline identical to R10 (3-slot ring, GLL, vmcnt(2), 1 barrier).
__global__ __launch_bounds__(256, 4) void k_main(
    const float* __restrict__ edge, const unsigned char* __restrict__ ws_adj,
    const short* __restrict__ ws_B,
    const float* __restrict__ ws_c, const unsigned short* __restrict__ ws_mh2,
    float* __restrict__ pbuf, int reps) {
  __shared__ __align__(16) char smem[3 * 8192 + 8192 + 512];
  char* ring    = smem;
  char* mh_lds  = smem + 24576;
  char* adj_lds = smem + 24576 + 8192;
  const int lane = threadIdx.x & 63;
  const int w = threadIdx.x >> 6;
  const int wg = blockIdx.x;
  const int b   = wg & 7;          // XCD-aligned batch
  const int j16 = (wg >> 3) & 15;
  const int s   = wg >> 7;         // i-interleave class: i = s + 8t
  const int j0 = j16 * 16;
  const int n0 = w * 32;
  const int lr = lane & 15;
  const int lg = lane >> 4;

  s16x8 bfrag[4][2];
#pragma unroll
  for (int kb = 0; kb < 4; ++kb)
#pragma unroll
    for (int nb = 0; nb < 2; ++nb)
      bfrag[kb][nb] = *reinterpret_cast<const s16x8*>(
          ws_B + ((kb * 8 + w * 2 + nb) * 64 + lane) * 8);

  float cf[2][4];
#pragma unroll
  for (int nb = 0; nb < 2; ++nb)
#pragma unroll
    for (int r = 0; r < 4; ++r)
      cf[nb][r] = ws_c[(b * N_ + j0 + lg * 4 + r) * C_ + n0 + nb * 16 + lr];

  // step t reads i = s + 8t: base at i=s, stride 8*STEPB = 1MB
  const char* gedge = (const char*)(edge + ((size_t)(b * N_ + s) * N_ + j0) * C_);

  int soff[2];
#pragma unroll
  for (int q = 0; q < 2; ++q) {
    int y = w * 2048 + q * 1024 + lane * 16;
    int row = y >> 9;
    soff[q] = y ^ ((row & 7) << 4);
  }
  const int base0 = lr * 512 + lg * 32;
  const int swz = (lr & 7) << 4;

#define GLL16(GP, LP) __builtin_amdgcn_global_load_lds((gas_void*)(GP), (las_void*)(LP), 16, 0, 0)
#define GLL4(GP, LP)  __builtin_amdgcn_global_load_lds((gas_void*)(GP), (las_void*)(LP), 4, 0, 0)

#define ISSUE(SL, TT) do { \
    const char* gch = gedge + (size_t)(TT) * 8 * STEPB; \
    char* lb = ring + (SL) * 8192 + w * 2048; \
    GLL16(gch + soff[0], lb); \
    GLL16(gch + soff[1], lb + 1024); \
  } while (0)

#define STEP(SL, ISL, WAITN, DOISSUE, TI, T) do { \
    asm volatile("s_waitcnt vmcnt(" WAITN ")\n\ts_barrier" ::: "memory"); \
    if (DOISSUE) ISSUE(ISL, TI); \
    const char* rb = ring + (SL) * 8192; \
    s16x8 af[4]; \
    _Pragma("unroll") \
    for (int kb = 0; kb < 4; ++kb) { \
      int a0 = (base0 + kb * 128) ^ swz; \
      f32x4 lo = *reinterpret_cast<const f32x4*>(rb + a0); \
      f32x4 hi = *reinterpret_cast<const f32x4*>(rb + (a0 ^ 16)); \
      af[kb] = cvt8(lo, hi); \
    } \
    unsigned int mw = *reinterpret_cast<const unsigned int*>(mh_lds + (T) * 256 + w * 64 + lr * 4); \
    unsigned int ab = *reinterpret_cast<const unsigned int*>(adj_lds + (T) * 16 + lg * 4); \
    float mh0 = __builtin_bit_cast(float, mw << 16); \
    float mh1 = __builtin_bit_cast(float, mw & 0xffff0000u); \
    float adjf[4] = {(float)(ab & 0xff), (float)((ab >> 8) & 0xff), \
                     (float)((ab >> 16) & 0xff), (float)(ab >> 24)}; \
    _Pragma("unroll") \
    for (int nb = 0; nb < 2; ++nb) { \
      f32x4 acc; \
      float mhv = nb ? mh1 : mh0; \
      _Pragma("unroll") \
      for (int r = 0; r < 4; ++r) acc[r] = cf[nb][r] + mhv; \
      _Pragma("unroll") \
      for (int kb = 0; kb < 4; ++kb) \
        acc = __builtin_amdgcn_mfma_f32_16x16x32_bf16(af[kb], bfrag[kb][nb], acc, 0, 0, 0); \
      _Pragma("unroll") \
      for (int r = 0; r < 4; ++r) mx[nb][r] = fmaxf(mx[nb][r], adjf[r] * acc[r]); \
    } \
  } while (0)

  for (int rep = 0; rep < reps; ++rep) {
    f32x4 mx[2];
#pragma unroll
    for (int nb = 0; nb < 2; ++nb)
#pragma unroll
      for (int r = 0; r < 4; ++r) mx[nb][r] = -INFINITY;

    {
      // stage mh rows i = s+8T (T=0..31): wave w stages T = w*8+q*4+(lane>>4)
      const char* mh_g = (const char*)(ws_mh2 + (size_t)b * N_ * C_);
#pragma unroll
      for (int q = 0; q < 2; ++q) {
        int T = w * 8 + q * 4 + (lane >> 4);
        GLL16(mh_g + ((size_t)(s + 8 * T)) * 256 + (lane & 15) * 16,
              mh_lds + w * 2048 + q * 1024);
      }
      // adj rows i = s+8T, 16B each (j0..j0+16)
      const char* adj_g = (const char*)(ws_adj + (size_t)b * N_ * N_ + j0);
      GLL4(adj_g + ((size_t)(s + 8 * (lane >> 2))) * N_ + (lane & 3) * 4, adj_lds);
      GLL4(adj_g + ((size_t)(s + 8 * (16 + (lane >> 2)))) * N_ + (lane & 3) * 4, adj_lds + 256);
    }
    ISSUE(0, 0);
    ISSUE(1, 1);
    asm volatile("s_waitcnt vmcnt(4)\n\ts_barrier" ::: "memory");

    for (int o = 0; o < 10; ++o) {
      STEP(0, 2, "2", 1, 3 * o + 2, 3 * o);
      STEP(1, 0, "2", 1, 3 * o + 3, 3 * o + 1);
      STEP(2, 1, "2", 1, 3 * o + 4, 3 * o + 2);
    }
    STEP(0, 2, "2", 0, 0, 30);
    STEP(1, 0, "0", 0, 0, 31);

    float* prow = pbuf + (((size_t)s * B_ + b) * N_ + j0 + lg * 4) * C_ + n0 + lr;
#pragma unroll
    for (int nb = 0; nb < 2; ++nb)
#pragma unroll
      for (int r = 0; r < 4; ++r)
        prow[r * C_ + nb * 16] = mx[nb][r];
  }

#undef STEP
#undef ISSUE
#undef GLL16
#undef GLL4
}

// ---------- Epilogue: S-max + node@Wo1 + hidden@Wo2 + msgs@Wo3 ----------
__global__ void k_epi(const float* __restrict__ node, const float* __restrict__ hidden,
                      const float* __restrict__ Wo1, const float* __restrict__ bo1,
                      const float* __restrict__ Wo2, const float* __restrict__ bo2,
                      const float* __restrict__ Wo3, const float* __restrict__ bo3,
                      const float* __restrict__ pbuf, float* __restrict__ out, int reps) {
  int row0 = blockIdx.x * 4;
  int col = threadIdx.x & 127;
  int half = threadIdx.x >> 7;
  __shared__ float shn[4][C_], shh[4][C_], shm[4][C_];
  for (int rep = 0; rep < reps; ++rep) {
#pragma unroll
    for (int r = 0; r < 2; ++r) {
      int rr = half * 2 + r;
      shn[rr][col] = node[(row0 + rr) * C_ + col];
      shh[rr][col] = hidden[(row0 + rr) * C_ + col];
      float mv = -INFINITY;
#pragma unroll
      for (int s = 0; s < S_; ++s)
        mv = fmaxf(mv, pbuf[((size_t)s * (B_ * N_) + row0 + rr) * C_ + col]);
      shm[rr][col] = mv;
    }
    __syncthreads();
    float init = bo1[col] + bo2[col] + bo3[col];
    float acc[2];
    acc[0] = init; acc[1] = init;
    for (int k = 0; k < C_; k += 8) {
      float wv1[8], wv2[8], wv3[8];
#pragma unroll
      for (int u = 0; u < 8; ++u) {
        wv1[u] = Wo1[(k + u) * C_ + col];
        wv2[u] = Wo2[(k + u) * C_ + col];
        wv3[u] = Wo3[(k + u) * C_ + col];
      }
#pragma unroll
      for (int u = 0; u < 8; ++u)
#pragma unroll
        for (int r = 0; r < 2; ++r) {
          int rr = half * 2 + r;
          acc[r] += shn[rr][k + u] * wv1[u] + shh[rr][k + u] * wv2[u] + shm[rr][k + u] * wv3[u];
        }
    }
#pragma unroll
    for (int r = 0; r < 2; ++r)
      out[(row0 + half * 2 + r) * C_ + col] = acc[r];
    __syncthreads();
  }
}

extern "C" void kernel_launch(void* const* d_in, const int* in_sizes, int n_in,
                              void* d_out, int out_size, void* d_ws, size_t ws_size,
                              hipStream_t stream) {
  const float* node   = (const float*)d_in[0];
  const float* edge   = (const float*)d_in[1];
  const float* graph  = (const float*)d_in[2];
  const int*   adjm   = (const int*)d_in[3];
  const float* hidden = (const float*)d_in[4];
  const float* Wn = (const float*)d_in[5];  const float* bn = (const float*)d_in[6];
  const float* Wh = (const float*)d_in[7];  const float* bh = (const float*)d_in[8];
  const float* We = (const float*)d_in[9];  const float* be = (const float*)d_in[10];
  const float* Wg = (const float*)d_in[11]; const float* bg = (const float*)d_in[12];
  const float* Wo1 = (const float*)d_in[13]; const float* bo1 = (const float*)d_in[14];
  const float* Wo2 = (const float*)d_in[15]; const float* bo2 = (const float*)d_in[16];
  const float* Wo3 = (const float*)d_in[17]; const float* bo3 = (const float*)d_in[18];
  float* out = (float*)d_out;

  char* ws = (char*)d_ws;
  float*          ws_c   = (float*)ws;                            // 1 MB
  unsigned short* ws_mh2 = (unsigned short*)(ws + (1u << 20));    // 512 KB (bf16)
  short*          ws_B   = (short*)(ws + 1572864u);               // 32 KB
  unsigned char*  ws_adj = (unsigned char*)(ws + 1835008u);       // 512 KB
  float*          pbuf   = (float*)(ws + (4u << 20));             // 8 MB partials

  k_pro<<<1056, 128, 0, stream>>>(node, hidden, graph, adjm, Wn, bn, Wh, bh, be,
                                  Wg, bg, We, ws_c, ws_mh2, ws_B, ws_adj, 1);
  k_main<<<1024, 256, 0, stream>>>(edge, ws_adj, ws_B, ws_c, ws_mh2, pbuf, 1);
  k_epi<<<512, 256, 0, stream>>>(node, hidden, Wo1, bo1, Wo2, bo2, Wo3, bo3,
                                 pbuf, out, 1);
}